// Round 2
// baseline (82.213 us; speedup 1.0000x reference)
//
#include <hip/hip_runtime.h>

#define NNODES 1024
#define NHEADS 8
#define NHID 16
#define DIM 128            // NHEADS * NHID
#define NEG_SLOPE 0.2f

// quad broadcast via DPP quad_perm
template<int CTRL>
__device__ __forceinline__ float qbcast(float v) {
    return __int_as_float(__builtin_amdgcn_mov_dpp(__float_as_int(v), CTRL, 0xF, 0xF, true));
}

// K1: g = h @ W^T tiled 16(i) x 16(one head); src/dst reductions fused.
__global__ __launch_bounds__(256) void proj_kernel(
    const float* __restrict__ h, const float* __restrict__ W,
    const float* __restrict__ attn_w,
    float* __restrict__ g, float* __restrict__ srcv, float* __restrict__ dstv)
{
    const int bi = blockIdx.x & 63;   // i-tile
    const int bh = blockIdx.x >> 6;   // head
    const int i0 = bi << 4;
    const int tid = threadIdx.x;
    __shared__ float4 hs[16][33];
    __shared__ float4 ws[16][33];
    const float4* h4 = (const float4*)h;   // 32 float4 per row
    const float4* W4 = (const float4*)W;
    {
        const int t0 = tid, t1 = tid + 256;
        hs[t0 >> 5][t0 & 31] = h4[(size_t)i0 * 32 + t0];
        hs[t1 >> 5][t1 & 31] = h4[(size_t)i0 * 32 + t1];
        ws[t0 >> 5][t0 & 31] = W4[(size_t)(bh * 16) * 32 + t0];
        ws[t1 >> 5][t1 & 31] = W4[(size_t)(bh * 16) * 32 + t1];
    }
    __syncthreads();
    const int il = tid >> 4;          // 0..15 local row
    const int f  = tid & 15;          // 0..15 feature within head
    float acc = 0.f;
#pragma unroll
    for (int k = 0; k < 32; k++) {
        const float4 a = hs[il][k];
        const float4 b = ws[f][k];
        acc = fmaf(a.x, b.x, fmaf(a.y, b.y, fmaf(a.z, b.z, fmaf(a.w, b.w, acc))));
    }
    const int i = i0 + il;
    g[(size_t)i * DIM + bh * NHID + f] = acc;
    float sv = acc * attn_w[f];
    float dv = acc * attn_w[NHID + f];
#pragma unroll
    for (int off = 1; off <= 8; off <<= 1) {
        sv += __shfl_xor(sv, off, 64);
        dv += __shfl_xor(dv, off, 64);
    }
    if (f == 0) { srcv[i * NHEADS + bh] = sv; dstv[i * NHEADS + bh] = dv; }
}

// K2: 4 rows per block, 1024 threads (16 waves, 1 block/CU, 4 waves/SIMD).
// Each g-load float4 now feeds 4 output rows -> L2 g-traffic halves vs R=2.
// Lane->j remap: jw = (tg*32+jsB)*4 + qB (consecutive j within a quad):
//   dstL read 2-way (free), evL read conflict-free, DPP lane K == load row +K.
__global__ __launch_bounds__(1024, 4) void fused_kernel(
    const int* __restrict__ adj, const float* __restrict__ s,
    const float* __restrict__ g, const float* __restrict__ srcv,
    const float* __restrict__ dstv, float* __restrict__ out)
{
    const int i0   = blockIdx.x * 4;
    const int tid  = threadIdx.x;
    const int lane = tid & 63;
    const int wv   = tid >> 6;            // wave 0..15

    __shared__ float evL[4][NNODES];          // 16 KB: adj ? exp(s) : 0
    __shared__ float dstL[NNODES * NHEADS];   // 32 KB staged dstv
    __shared__ float sh_src[4][NHEADS];
    __shared__ float zeA[16][NHEADS][4];      // 2 KB
    __shared__ float zsA[16];
    __shared__ float statE[4][NHEADS];
    __shared__ float statS[4];
    __shared__ float redO[16][4][NHEADS][4][4];  // 32 KB
    __shared__ float ztA[16][4][NHEADS];      // 2 KB

    // ---- Phase A1: ev into LDS; zs partial; stage dstv + srcv ----
    const int rA = tid >> 8;              // 0..3 (uniform per wave)
    const int cA = tid & 255;
    float zs;
    {
        const int4   a  = ((const int4*)  adj)[(size_t)(i0 + rA) * (NNODES/4) + cA];
        const float4 sv = ((const float4*)s  )[(size_t)(i0 + rA) * (NNODES/4) + cA];
        float4 e4;
        e4.x = a.x ? __expf(sv.x) : 0.f;
        e4.y = a.y ? __expf(sv.y) : 0.f;
        e4.z = a.z ? __expf(sv.z) : 0.f;
        e4.w = a.w ? __expf(sv.w) : 0.f;
        ((float4*)evL[rA])[cA] = e4;
        zs = e4.x + e4.y + e4.z + e4.w;
    }
    {
        const float4* dv4 = (const float4*)dstv;
        float4* dl4 = (float4*)dstL;
#pragma unroll
        for (int k = 0; k < 2; k++) dl4[k * 1024 + tid] = dv4[k * 1024 + tid];
        if (tid < 32) sh_src[tid >> 3][tid & 7] =
            srcv[(size_t)(i0 + (tid >> 3)) * NHEADS + (tid & 7)];
    }
#pragma unroll
    for (int off = 1; off <= 32; off <<= 1) zs += __shfl_xor(zs, off, 64);
    if (lane == 0) zsA[wv] = zs;          // wave's row is rA (uniform per wave)
    __syncthreads();

    // ---- Phase A2: ze[r][h] over unmasked j ----
    const int hA  = tid & 7;
    const int jsA = tid >> 3;             // 0..127
    float ze[4] = {0.f, 0.f, 0.f, 0.f};
    {
        const float sH[4] = { sh_src[0][hA], sh_src[1][hA],
                              sh_src[2][hA], sh_src[3][hA] };
#pragma unroll 4
        for (int t = 0; t < 8; t++) {
            const int j = t * 128 + jsA;
            const float d = dstL[j * NHEADS + hA];
#pragma unroll
            for (int r = 0; r < 4; r++) {
                float e = sH[r] + d;
                e = e > 0.f ? e : NEG_SLOPE * e;
                ze[r] += (evL[r][j] != 0.f) ? __expf(e) : 0.f;
            }
        }
    }
#pragma unroll
    for (int off = 8; off <= 32; off <<= 1)
#pragma unroll
        for (int r = 0; r < 4; r++) ze[r] += __shfl_xor(ze[r], off, 64);
    if (lane < NHEADS) {
#pragma unroll
        for (int r = 0; r < 4; r++) zeA[wv][lane][r] = ze[r];
    }
    __syncthreads();
    if (tid < 32) {
        const int hh = tid & 7, rr = tid >> 3;
        float z = 0.f;
#pragma unroll
        for (int w2 = 0; w2 < 16; w2++) z += zeA[w2][hh][rr];
        statE[rr][hh] = 1.f / z;
    } else if (tid < 36) {
        const int rr = tid - 32;
        statS[rr] = 1.f / (zsA[rr*4] + zsA[rr*4+1] + zsA[rr*4+2] + zsA[rr*4+3]);
    }
    __syncthreads();

    // ---- Phase B: tid = jsB*32 + hB*4 + qB ----
    const int qB  = tid & 3;
    const int hB  = (tid >> 2) & 7;
    const int jsB = tid >> 5;             // 0..31
    const float ize[4] = { statE[0][hB], statE[1][hB], statE[2][hB], statE[3][hB] };
    const float izs[4] = { statS[0], statS[1], statS[2], statS[3] };
    const float sB[4]  = { sh_src[0][hB], sh_src[1][hB], sh_src[2][hB], sh_src[3][hB] };

    float acc[4][4] = {{0.f,0.f,0.f,0.f},{0.f,0.f,0.f,0.f},
                       {0.f,0.f,0.f,0.f},{0.f,0.f,0.f,0.f}};
    float zt[4] = {0.f, 0.f, 0.f, 0.f};
    const float4* g4 = (const float4*)g;
    const int rowb0 = jsB * 4;            // + tg*128 (+K selects row)
    const int fq    = hB * 4 + qB;        // float4 slot within a row

#pragma unroll 2
    for (int tg = 0; tg < 8; tg++) {
        const int jw = tg * 128 + rowb0 + qB;
        const float d = dstL[jw * NHEADS + hB];
        float w[4];
#pragma unroll
        for (int r = 0; r < 4; r++) {
            float e = sB[r] + d;
            e = e > 0.f ? e : NEG_SLOPE * e;
            const float x  = __expf(e);
            const float ev = evL[r][jw];
            const float arg = (ev != 0.f) ? fmaf(x, ize[r], ev * izs[r]) : 0.f;
            w[r] = __expf(arg);           // exp(0)=1 at masked positions
            zt[r] += w[r];
        }
#define KSTEP(K, CTRL)                                                        \
        {                                                                     \
            const int j = tg * 128 + rowb0 + (K);                             \
            const float4 gv = g4[(size_t)j * 32 + fq];                        \
            const float wk0 = qbcast<CTRL>(w[0]);                             \
            const float wk1 = qbcast<CTRL>(w[1]);                             \
            const float wk2 = qbcast<CTRL>(w[2]);                             \
            const float wk3 = qbcast<CTRL>(w[3]);                             \
            acc[0][0] = fmaf(wk0, gv.x, acc[0][0]);                           \
            acc[0][1] = fmaf(wk0, gv.y, acc[0][1]);                           \
            acc[0][2] = fmaf(wk0, gv.z, acc[0][2]);                           \
            acc[0][3] = fmaf(wk0, gv.w, acc[0][3]);                           \
            acc[1][0] = fmaf(wk1, gv.x, acc[1][0]);                           \
            acc[1][1] = fmaf(wk1, gv.y, acc[1][1]);                           \
            acc[1][2] = fmaf(wk1, gv.z, acc[1][2]);                           \
            acc[1][3] = fmaf(wk1, gv.w, acc[1][3]);                           \
            acc[2][0] = fmaf(wk2, gv.x, acc[2][0]);                           \
            acc[2][1] = fmaf(wk2, gv.y, acc[2][1]);                           \
            acc[2][2] = fmaf(wk2, gv.z, acc[2][2]);                           \
            acc[2][3] = fmaf(wk2, gv.w, acc[2][3]);                           \
            acc[3][0] = fmaf(wk3, gv.x, acc[3][0]);                           \
            acc[3][1] = fmaf(wk3, gv.y, acc[3][1]);                           \
            acc[3][2] = fmaf(wk3, gv.z, acc[3][2]);                           \
            acc[3][3] = fmaf(wk3, gv.w, acc[3][3]);                           \
        }
        KSTEP(0, 0x00)
        KSTEP(1, 0x55)
        KSTEP(2, 0xAA)
        KSTEP(3, 0xFF)
#undef KSTEP
    }

    // ---- Epilogue ----
#pragma unroll
    for (int r = 0; r < 4; r++)
#pragma unroll
        for (int m = 0; m < 4; m++) acc[r][m] += __shfl_xor(acc[r][m], 32, 64);
#pragma unroll
    for (int r = 0; r < 4; r++) {
        zt[r] += __shfl_xor(zt[r], 1, 64);
        zt[r] += __shfl_xor(zt[r], 2, 64);
        zt[r] += __shfl_xor(zt[r], 32, 64);
    }
    if (lane < 32) {
#pragma unroll
        for (int r = 0; r < 4; r++)
            *(float4*)&redO[wv][r][hB][qB][0] =
                make_float4(acc[r][0], acc[r][1], acc[r][2], acc[r][3]);
        if ((lane & 3) == 0) {
#pragma unroll
            for (int r = 0; r < 4; r++) ztA[wv][r][hB] = zt[r];
        }
    }
    __syncthreads();
    if (tid < 512) {
        const int rr = tid >> 7;          // 0..3
        const int hf = tid & 127;
        const int oh = hf >> 4;
        const int qq = (hf >> 2) & 3;
        const int mm = hf & 3;
        float v = 0.f, z = 0.f;
#pragma unroll
        for (int w2 = 0; w2 < 16; w2++) {
            v += redO[w2][rr][oh][qq][mm];
            z += ztA[w2][rr][oh];
        }
        out[(size_t)(i0 + rr) * DIM + hf] = v / z;
    }
}

extern "C" void kernel_launch(void* const* d_in, const int* in_sizes, int n_in,
                              void* d_out, int out_size, void* d_ws, size_t ws_size,
                              hipStream_t stream) {
    const float* h      = (const float*)d_in[0];
    const int*   adj    = (const int*)  d_in[1];
    const float* s      = (const float*)d_in[2];
    const float* W      = (const float*)d_in[3];
    const float* attn_w = (const float*)d_in[4];
    float* out = (float*)d_out;

    float* g    = (float*)d_ws;                      // 1024*128
    float* srcv = g    + (size_t)NNODES * DIM;       // 1024*8
    float* dstv = srcv + (size_t)NNODES * NHEADS;    // 1024*8

    proj_kernel <<<512, 256, 0, stream>>>(h, W, attn_w, g, srcv, dstv);
    fused_kernel<<<NNODES / 4, 1024, 0, stream>>>(adj, s, g, srcv, dstv, out);
}